// Round 1
// baseline (237.274 us; speedup 1.0000x reference)
//
#include <hip/hip_runtime.h>

#define N_NODES 6144
#define ATTD 128
#define HIDD 96
#define EPT 100000
#define NTYPE 3
#define NEDGE (NTYPE * EPT)
#define HBITS 20
#define HSIZE (1u << HBITS)
#define HMASK (HSIZE - 1)
#define NEG 0.2f

// ---------------- params: per (l,h): {w0, w_last, es0, es1, es2} ----------------
__global__ void k_params(const float* __restrict__ attn_w,
                         const float* __restrict__ edge_emb,
                         float* __restrict__ params, float* __restrict__ stot) {
    int i = threadIdx.x;
    if (i < 2) stot[i] = 0.f;
    if (i < 4) {
        // attn_w flat: (2,2,22,1) -> (l*2+h)*22 + j
        const float* w = attn_w + i * 22;
        float* p = params + i * 8;
        p[0] = w[0];    // w0 (src coeff)
        p[1] = w[21];   // w_last (tgt coeff)
        for (int t = 0; t < NTYPE; ++t) {
            float acc = 0.f;
            for (int j = 0; j < 20; ++j) acc += edge_emb[t * 20 + j] * w[1 + j];
            p[2 + t] = acc;
        }
    }
}

// ---------------- hash init ----------------
__global__ void k_hash_init(int* __restrict__ hkey, int* __restrict__ hcnt) {
    int i = blockIdx.x * blockDim.x + threadIdx.x;
    if (i < (int)HSIZE) { hkey[i] = -1; hcnt[i] = 0; }
}

// ---------------- insert edges, dedupe by (src,tgt), count per type ----------------
__global__ void k_insert(const int* __restrict__ edges,
                         int* __restrict__ hkey, int* __restrict__ hcnt) {
    int k = blockIdx.x * blockDim.x + threadIdx.x;
    if (k >= NEDGE) return;
    int t = k / EPT;
    int e = k - t * EPT;
    int src = edges[t * (2 * EPT) + e];
    int tgt = edges[t * (2 * EPT) + EPT + e];
    int key = (src << 13) | tgt;   // both < 8192
    unsigned slot = ((unsigned)key * 2654435761u) >> (32 - HBITS);
    while (true) {
        int prev = atomicCAS(&hkey[slot], -1, key);
        if (prev == -1 || prev == key) break;
        slot = (slot + 1) & HMASK;
    }
    atomicAdd(&hcnt[slot], 1 << (10 * t));  // packed 3x10-bit type counts
}

// ---------------- MLP scores: s = leaky(X@W1+b1)@W2 + b2 ----------------
__global__ void k_mlp(const float* __restrict__ X, const float* __restrict__ W1,
                      const float* __restrict__ b1, const float* __restrict__ W2,
                      const float* __restrict__ b2, float* __restrict__ s) {
    int row = blockIdx.x;
    int tid = threadIdx.x;
    __shared__ float xs[ATTD];
    xs[tid] = X[row * ATTD + tid];
    __syncthreads();
    float val = 0.f;
    if (tid < HIDD) {
        float acc = b1[tid];
#pragma unroll
        for (int k = 0; k < ATTD; ++k) acc += xs[k] * W1[k * HIDD + tid];
        float h = acc > 0.f ? acc : NEG * acc;
        val = h * W2[tid];
    }
#pragma unroll
    for (int off = 32; off; off >>= 1) val += __shfl_down(val, off, 64);
    __shared__ float red[2];
    if ((tid & 63) == 0) red[tid >> 6] = val;
    __syncthreads();
    if (tid == 0) s[row] = red[0] + red[1] + b2[0];
}

// ---------------- per-layer prep: zero num/den, reduce S_total ----------------
__global__ void k_prep(const float* __restrict__ s, float* __restrict__ num0,
                       float* __restrict__ den0, float* __restrict__ num1,
                       float* __restrict__ den1, float* __restrict__ stot_l) {
    int i = blockIdx.x * blockDim.x + threadIdx.x;
    float v = 0.f;
    if (i < N_NODES) {
        num0[i] = 0.f; den0[i] = 0.f; num1[i] = 0.f; den1[i] = 0.f;
        v = s[i];
    }
#pragma unroll
    for (int off = 32; off; off >>= 1) v += __shfl_down(v, off, 64);
    __shared__ float red[4];
    if ((threadIdx.x & 63) == 0) red[threadIdx.x >> 6] = v;
    __syncthreads();
    if (threadIdx.x == 0) {
        float t = red[0] + red[1] + red[2] + red[3];
        atomicAdd(stot_l, t);
    }
}

// ---------------- sweep hash slots, accumulate num/den for both heads ----------------
__global__ void k_accum(const int* __restrict__ hkey, const int* __restrict__ hcnt,
                        const float* __restrict__ s, const float* __restrict__ params,
                        float* __restrict__ num0, float* __restrict__ den0,
                        float* __restrict__ num1, float* __restrict__ den1, int l) {
    int i = blockIdx.x * blockDim.x + threadIdx.x;
    if (i >= (int)HSIZE) return;
    int key = hkey[i];
    if (key < 0) return;
    int cw = hcnt[i];
    int u = key >> 13, v = key & 8191;
    float c0 = (float)(cw & 1023);
    float c1 = (float)((cw >> 10) & 1023);
    float c2 = (float)((cw >> 20) & 1023);
    float C = c0 + c1 + c2;
    float su = s[u], sv = s[v];
    const float* p0 = params + (l * 2 + 0) * 8;
    const float* p1 = params + (l * 2 + 1) * 8;
    {
        float A = C * (p0[0] * su + p0[1] * sv) + c0 * p0[2] + c1 * p0[3] + c2 * p0[4];
        float la = A > 0.f ? A : NEG * A;
        float g = expf(la) - 1.f;
        atomicAdd(&num0[u], g * sv);
        atomicAdd(&den0[u], g);
    }
    {
        float A = C * (p1[0] * su + p1[1] * sv) + c0 * p1[2] + c1 * p1[3] + c2 * p1[4];
        float la = A > 0.f ? A : NEG * A;
        float g = expf(la) - 1.f;
        atomicAdd(&num1[u], g * sv);
        atomicAdd(&den1[u], g);
    }
}

// ---------------- combine: s_new = 0.5 * sum_h (S + num_h) / (N + den_h) ----------------
__global__ void k_combine(const float* __restrict__ stot_l,
                          const float* __restrict__ num0, const float* __restrict__ den0,
                          const float* __restrict__ num1, const float* __restrict__ den1,
                          float* __restrict__ dst) {
    int u = blockIdx.x * blockDim.x + threadIdx.x;
    if (u < N_NODES) {
        float S = *stot_l;
        float r0 = (S + num0[u]) / ((float)N_NODES + den0[u]);
        float r1 = (S + num1[u]) / ((float)N_NODES + den1[u]);
        dst[u] = 0.5f * (r0 + r1);
    }
}

extern "C" void kernel_launch(void* const* d_in, const int* in_sizes, int n_in,
                              void* d_out, int out_size, void* d_ws, size_t ws_size,
                              hipStream_t stream) {
    const float* X        = (const float*)d_in[0];
    const int*   edges    = (const int*)d_in[1];
    const float* W1       = (const float*)d_in[2];
    const float* b1       = (const float*)d_in[3];
    const float* W2       = (const float*)d_in[4];
    const float* b2       = (const float*)d_in[5];
    const float* edge_emb = (const float*)d_in[6];
    const float* attn_w   = (const float*)d_in[7];
    float* out = (float*)d_out;

    char* w = (char*)d_ws;
    float* params = (float*)w; w += 256;
    float* stot   = (float*)w; w += 256;
    float* s      = (float*)w; w += N_NODES * sizeof(float);
    float* num0   = (float*)w; w += N_NODES * sizeof(float);
    float* den0   = (float*)w; w += N_NODES * sizeof(float);
    float* num1   = (float*)w; w += N_NODES * sizeof(float);
    float* den1   = (float*)w; w += N_NODES * sizeof(float);
    int*   hkey   = (int*)w;   w += HSIZE * sizeof(int);
    int*   hcnt   = (int*)w;

    k_params<<<1, 64, 0, stream>>>(attn_w, edge_emb, params, stot);
    k_hash_init<<<HSIZE / 256, 256, 0, stream>>>(hkey, hcnt);
    k_insert<<<(NEDGE + 255) / 256, 256, 0, stream>>>(edges, hkey, hcnt);
    k_mlp<<<N_NODES, ATTD, 0, stream>>>(X, W1, b1, W2, b2, s);

    for (int l = 0; l < 2; ++l) {
        k_prep<<<N_NODES / 256, 256, 0, stream>>>(s, num0, den0, num1, den1, &stot[l]);
        k_accum<<<HSIZE / 256, 256, 0, stream>>>(hkey, hcnt, s, params,
                                                 num0, den0, num1, den1, l);
        k_combine<<<N_NODES / 256, 256, 0, stream>>>(&stot[l], num0, den0, num1, den1,
                                                     l == 0 ? s : out);
    }
}